// Round 1
// baseline (270.666 us; speedup 1.0000x reference)
//
#include <hip/hip_runtime.h>

#define NF 512
// 1/sqrt(512)
#define SCALE 0.044194173824159216f

__device__ __forceinline__ void wht512(float r[8], const int lane) {
    // Intra-lane stages: strides 1,2,4 over the 8 consecutive elements this lane owns.
#pragma unroll
    for (int s = 1; s < 8; s <<= 1) {
#pragma unroll
        for (int j = 0; j < 8; ++j) {
            if (!(j & s)) {
                const float u = r[j], w = r[j | s];
                r[j] = u + w;
                r[j | s] = u - w;
            }
        }
    }
    // Cross-lane stages: strides 8..256 -> lane-xor masks 1..32.
#pragma unroll
    for (int m = 1; m <= 32; m <<= 1) {
        const float sgn = (lane & m) ? -1.0f : 1.0f;
#pragma unroll
        for (int j = 0; j < 8; ++j) {
            const float p = __shfl_xor(r[j], m, 64);
            // bit clear: r + p ; bit set: p - r  (exact, sgn = +/-1)
            r[j] = fmaf(sgn, r[j], p);
        }
    }
}

__global__ __launch_bounds__(256, 4)
void wht512_soft_kernel(const float* __restrict__ x,
                        const float* __restrict__ gate,
                        const float* __restrict__ thr,
                        float* __restrict__ out,
                        const int nrows) {
    const int lane = threadIdx.x & 63;
    const int wave = blockIdx.x * (blockDim.x >> 6) + (threadIdx.x >> 6);
    const int nwaves = gridDim.x * (blockDim.x >> 6);

    // Per-lane gate (with first 1/sqrt(n) folded in) and threshold for features lane*8+j.
    float vg[8], tg[8];
    {
        const float4 a = ((const float4*)gate)[lane * 2];
        const float4 b = ((const float4*)gate)[lane * 2 + 1];
        vg[0] = a.x * SCALE; vg[1] = a.y * SCALE; vg[2] = a.z * SCALE; vg[3] = a.w * SCALE;
        vg[4] = b.x * SCALE; vg[5] = b.y * SCALE; vg[6] = b.z * SCALE; vg[7] = b.w * SCALE;
        const float4 c = ((const float4*)thr)[lane * 2];
        const float4 d = ((const float4*)thr)[lane * 2 + 1];
        tg[0] = c.x; tg[1] = c.y; tg[2] = c.z; tg[3] = c.w;
        tg[4] = d.x; tg[5] = d.y; tg[6] = d.z; tg[7] = d.w;
    }

    for (int row = wave; row < nrows; row += nwaves) {
        const float4* xr = (const float4*)(x + (size_t)row * NF);
        const float4 a = xr[lane * 2];
        const float4 b = xr[lane * 2 + 1];
        float r[8] = {a.x, a.y, a.z, a.w, b.x, b.y, b.z, b.w};
        float x0[8];
#pragma unroll
        for (int j = 0; j < 8; ++j) x0[j] = r[j];

        // f1 (unscaled): H x
        wht512(r, lane);

        // f2 = v * (f1/sqrt(n));  f3 = sign(f2)*relu(|f2|-T)
#pragma unroll
        for (int j = 0; j < 8; ++j) {
            const float f = r[j] * vg[j];
            const float mdiff = fabsf(f) - tg[j];
            r[j] = (mdiff > 0.0f) ? copysignf(mdiff, f) : 0.0f;
        }

        // f4 (unscaled): H f3
        wht512(r, lane);

        // out = f4/sqrt(n) + x
        float4 oa, ob;
        oa.x = fmaf(r[0], SCALE, x0[0]);
        oa.y = fmaf(r[1], SCALE, x0[1]);
        oa.z = fmaf(r[2], SCALE, x0[2]);
        oa.w = fmaf(r[3], SCALE, x0[3]);
        ob.x = fmaf(r[4], SCALE, x0[4]);
        ob.y = fmaf(r[5], SCALE, x0[5]);
        ob.z = fmaf(r[6], SCALE, x0[6]);
        ob.w = fmaf(r[7], SCALE, x0[7]);
        float4* orow = (float4*)(out + (size_t)row * NF);
        orow[lane * 2] = oa;
        orow[lane * 2 + 1] = ob;
    }
}

extern "C" void kernel_launch(void* const* d_in, const int* in_sizes, int n_in,
                              void* d_out, int out_size, void* d_ws, size_t ws_size,
                              hipStream_t stream) {
    const float* x = (const float*)d_in[0];
    const float* v = (const float*)d_in[1];
    const float* T = (const float*)d_in[2];
    float* out = (float*)d_out;

    const int nrows = in_sizes[0] / NF;  // 64*4096 = 262144

    dim3 block(256);
    dim3 grid(4096);  // 16384 waves, grid-stride 16 rows/wave
    hipLaunchKernelGGL(wht512_soft_kernel, grid, block, 0, stream, x, v, T, out, nrows);
}

// Round 3
// 216.229 us; speedup vs baseline: 1.2518x; 1.2518x over previous
//
#include <hip/hip_runtime.h>

#define NF 512
// 1/sqrt(512)
#define SCALE 0.044194173824159216f

#if defined(__has_builtin)
#  if __has_builtin(__builtin_amdgcn_permlane32_swap)
#    define HAVE_PL32 1
#  else
#    define HAVE_PL32 0
#  endif
#  if __has_builtin(__builtin_amdgcn_permlane16_swap)
#    define HAVE_PL16 1
#  else
#    define HAVE_PL16 0
#  endif
#else
#  define HAVE_PL32 0
#  define HAVE_PL16 0
#endif

typedef unsigned uint2v __attribute__((ext_vector_type(2)));

// DPP cross-lane move: dst[lane] = src[permuted lane] (within 16-lane rows / quads).
template<int CTRL>
__device__ __forceinline__ float dppf(float x) {
    const int xi = __float_as_int(x);
    return __int_as_float(__builtin_amdgcn_update_dpp(xi, xi, CTRL, 0xF, 0xF, true));
}

// ds_swizzle xor-mask move (BitMode: (xor<<10)|0x1F).
template<int PAT>
__device__ __forceinline__ float swzf(float x) {
    return __int_as_float(__builtin_amdgcn_ds_swizzle(__float_as_int(x), PAT));
}

#if HAVE_PL16
// Butterfly across lane-xor-16 for TWO registers using permlane16_swap pairs.
// swap(a,b): each lane ends with (lo,hi) = (own-row value, partner-row value);
// s=lo+hi, d=lo-hi; second swap(s,d) reassembles new a (sum side) and new b
// (diff side) back into the standard lane layout.
__device__ __forceinline__ void bfly16(float& a, float& b) {
    uint2v t = __builtin_amdgcn_permlane16_swap(__float_as_uint(a), __float_as_uint(b), false, false);
    const float lo = __uint_as_float(t[0]);
    const float hi = __uint_as_float(t[1]);
    const float s = lo + hi;
    const float d = lo - hi;
    uint2v u = __builtin_amdgcn_permlane16_swap(__float_as_uint(s), __float_as_uint(d), false, false);
    a = __uint_as_float(u[0]);
    b = __uint_as_float(u[1]);
}
#endif

#if HAVE_PL32
__device__ __forceinline__ void bfly32(float& a, float& b) {
    uint2v t = __builtin_amdgcn_permlane32_swap(__float_as_uint(a), __float_as_uint(b), false, false);
    const float lo = __uint_as_float(t[0]);
    const float hi = __uint_as_float(t[1]);
    const float s = lo + hi;
    const float d = lo - hi;
    uint2v u = __builtin_amdgcn_permlane32_swap(__float_as_uint(s), __float_as_uint(d), false, false);
    a = __uint_as_float(u[0]);
    b = __uint_as_float(u[1]);
}
#endif

__device__ __forceinline__ void wht512(float r[8], const float sg1, const float sg2,
                                       const float sg4, const float sg8, const float sg16,
                                       const float sg32) {
    (void)sg16; (void)sg32;
    // Intra-lane stages: feature strides 1,2,4 (this lane's 8 consecutive elements).
#pragma unroll
    for (int s = 1; s < 8; s <<= 1) {
#pragma unroll
        for (int j = 0; j < 8; ++j) {
            if (!(j & s)) {
                const float u = r[j], w = r[j | s];
                r[j] = u + w;
                r[j | s] = u - w;
            }
        }
    }
    // lane-xor 1 (feature stride 8): DPP quad_perm [1,0,3,2]
#pragma unroll
    for (int j = 0; j < 8; ++j) { const float p = dppf<0xB1>(r[j]); r[j] = fmaf(sg1, r[j], p); }
    // lane-xor 2: DPP quad_perm [2,3,0,1]
#pragma unroll
    for (int j = 0; j < 8; ++j) { const float p = dppf<0x4E>(r[j]); r[j] = fmaf(sg2, r[j], p); }
    // lane-xor 4: ds_swizzle xor-4
#pragma unroll
    for (int j = 0; j < 8; ++j) { const float p = swzf<0x101F>(r[j]); r[j] = fmaf(sg4, r[j], p); }
    // lane-xor 8: DPP row_ror:8 (rotate by 8 mod 16 == xor 8)
#pragma unroll
    for (int j = 0; j < 8; ++j) { const float p = dppf<0x128>(r[j]); r[j] = fmaf(sg8, r[j], p); }
    // lane-xor 16
#if HAVE_PL16
#pragma unroll
    for (int j = 0; j < 8; j += 2) bfly16(r[j], r[j + 1]);
#else
#pragma unroll
    for (int j = 0; j < 8; ++j) { const float p = swzf<0x401F>(r[j]); r[j] = fmaf(sg16, r[j], p); }
#endif
    // lane-xor 32
#if HAVE_PL32
#pragma unroll
    for (int j = 0; j < 8; j += 2) bfly32(r[j], r[j + 1]);
#else
#pragma unroll
    for (int j = 0; j < 8; ++j) { const float p = __shfl_xor(r[j], 32, 64); r[j] = fmaf(sg32, r[j], p); }
#endif
}

__global__ __launch_bounds__(256, 4)
void wht512_soft_kernel(const float* __restrict__ x,
                        const float* __restrict__ gate,
                        const float* __restrict__ thr,
                        float* __restrict__ out,
                        const int nrows) {
    const int lane = threadIdx.x & 63;
    const int wave = blockIdx.x * (blockDim.x >> 6) + (threadIdx.x >> 6);
    const int nwaves = gridDim.x * (blockDim.x >> 6);

    const float sg1  = (lane & 1)  ? -1.0f : 1.0f;
    const float sg2  = (lane & 2)  ? -1.0f : 1.0f;
    const float sg4  = (lane & 4)  ? -1.0f : 1.0f;
    const float sg8  = (lane & 8)  ? -1.0f : 1.0f;
    const float sg16 = (lane & 16) ? -1.0f : 1.0f;
    const float sg32 = (lane & 32) ? -1.0f : 1.0f;

    // Per-lane gate (first 1/sqrt(n) folded in) and threshold, features lane*8+j.
    float vg[8], tg[8];
    {
        const float4 a = ((const float4*)gate)[lane * 2];
        const float4 b = ((const float4*)gate)[lane * 2 + 1];
        vg[0] = a.x * SCALE; vg[1] = a.y * SCALE; vg[2] = a.z * SCALE; vg[3] = a.w * SCALE;
        vg[4] = b.x * SCALE; vg[5] = b.y * SCALE; vg[6] = b.z * SCALE; vg[7] = b.w * SCALE;
        const float4 c = ((const float4*)thr)[lane * 2];
        const float4 d = ((const float4*)thr)[lane * 2 + 1];
        tg[0] = c.x; tg[1] = c.y; tg[2] = c.z; tg[3] = c.w;
        tg[4] = d.x; tg[5] = d.y; tg[6] = d.z; tg[7] = d.w;
    }

    int row = wave;
    float4 ca, cb;
    if (row < nrows) {
        const float4* xr = (const float4*)(x + (size_t)row * NF);
        ca = xr[lane * 2];
        cb = xr[lane * 2 + 1];
    }

    for (; row < nrows; row += nwaves) {
        // Prefetch next row before touching the current one (hide HBM latency).
        const int nrow = row + nwaves;
        float4 na = ca, nb = cb;
        if (nrow < nrows) {
            const float4* xn = (const float4*)(x + (size_t)nrow * NF);
            na = xn[lane * 2];
            nb = xn[lane * 2 + 1];
        }

        float r[8] = {ca.x, ca.y, ca.z, ca.w, cb.x, cb.y, cb.z, cb.w};

        // f1 (unscaled): H x
        wht512(r, sg1, sg2, sg4, sg8, sg16, sg32);

        // f2 = v * (f1/sqrt(n));  f3 = sign(f2)*relu(|f2|-T)
#pragma unroll
        for (int j = 0; j < 8; ++j) {
            const float f = r[j] * vg[j];
            const float mdiff = fabsf(f) - tg[j];
            r[j] = (mdiff > 0.0f) ? copysignf(mdiff, f) : 0.0f;
        }

        // f4 (unscaled): H f3
        wht512(r, sg1, sg2, sg4, sg8, sg16, sg32);

        // out = f4/sqrt(n) + x  (residual straight from the load regs)
        float4 oa, ob;
        oa.x = fmaf(r[0], SCALE, ca.x);
        oa.y = fmaf(r[1], SCALE, ca.y);
        oa.z = fmaf(r[2], SCALE, ca.z);
        oa.w = fmaf(r[3], SCALE, ca.w);
        ob.x = fmaf(r[4], SCALE, cb.x);
        ob.y = fmaf(r[5], SCALE, cb.y);
        ob.z = fmaf(r[6], SCALE, cb.z);
        ob.w = fmaf(r[7], SCALE, cb.w);
        float4* orow = (float4*)(out + (size_t)row * NF);
        orow[lane * 2] = oa;
        orow[lane * 2 + 1] = ob;

        ca = na;
        cb = nb;
    }
}

extern "C" void kernel_launch(void* const* d_in, const int* in_sizes, int n_in,
                              void* d_out, int out_size, void* d_ws, size_t ws_size,
                              hipStream_t stream) {
    const float* x = (const float*)d_in[0];
    const float* v = (const float*)d_in[1];
    const float* T = (const float*)d_in[2];
    float* out = (float*)d_out;

    const int nrows = in_sizes[0] / NF;  // 64*4096 = 262144

    dim3 block(256);
    dim3 grid(4096);  // 16384 waves, 16 rows/wave grid-stride
    hipLaunchKernelGGL(wht512_soft_kernel, grid, block, 0, stream, x, v, T, out, nrows);
}